// Round 1
// baseline (276.097 us; speedup 1.0000x reference)
//
#include <hip/hip_runtime.h>

// ---------- types ----------
typedef short short8 __attribute__((ext_vector_type(8)));        // 8 bf16 (4 VGPRs) MFMA A/B frag
typedef float floatx4 __attribute__((ext_vector_type(4)));       // MFMA C/D frag
typedef unsigned short ushortx4 __attribute__((ext_vector_type(4)));

__device__ __forceinline__ unsigned short f2bf(float f) {
    unsigned u = __float_as_uint(f);
    u += 0x7fffu + ((u >> 16) & 1u);   // RNE
    return (unsigned short)(u >> 16);
}

#define MFMA16(a, b, c) __builtin_amdgcn_mfma_f32_16x16x32_bf16((a), (b), (c), 0, 0, 0)

// ---------- problem sizes ----------
// N=8192, D_IN=1024, D_H=128
// ws layout (bytes)
static constexpr size_t H_OFF    = 0;                 // h bf16 [8192][128]      2 MB
static constexpr size_t Q_OFF    = 2097152;           // q*scale bf16 [8192][128]
static constexpr size_t K_OFF    = 4194304;           // k bf16 [8192][128]
static constexpr size_t VT_OFF   = 6291456;           // v^T bf16 [128][8192]
static constexpr size_t WFCT_OFF = 8388608;           // W_fc^T bf16 [128][1024]
static constexpr size_t WGT_OFF  = 8650752;           // W_gate^T bf16 [128][1024]
static constexpr size_t WQT_OFF  = 8912896;           // W_q^T bf16 [128][128]
static constexpr size_t WKT_OFF  = 8945664;
static constexpr size_t WVT_OFF  = 8978432;
static constexpr size_t LP_OFF   = 9011200;           // l partials fp32 [2*nsplit][8192] (max 16)
static constexpr size_t OP_OFF   = 9535488;           // O partials fp32 [nsplit][8192][128]

// log2(e)/sqrt(128): folded into stored q so P = exp2(S)
static constexpr float QSCALE = 0.1275174308f;

// ---------- K1: transpose + fp32->bf16 convert of weights ----------
__global__ void k_transw(const float* __restrict__ s, unsigned short* __restrict__ d, int K, int Nn) {
    int i = blockIdx.x * 256 + threadIdx.x;
    if (i < K * Nn) {
        int kk = i / Nn, nn = i - kk * Nn;
        d[(size_t)nn * K + kk] = f2bf(s[i]);
    }
}

// ---------- K2: h = (x@W_fc + b_fc) * sigmoid(x@W_gate + b_gate) ----------
// grid 256 blocks x 256 thr; block = 32 rows. wave(wr,wc): wc=0 -> fc, wc=1 -> gate; rows wr*16..+16
__global__ __launch_bounds__(256) void k_gated(const float* __restrict__ x,
                                               const unsigned short* __restrict__ wfct,
                                               const unsigned short* __restrict__ wgt,
                                               const float* __restrict__ bfc,
                                               const float* __restrict__ bg,
                                               unsigned short* __restrict__ h) {
    __shared__ __align__(16) unsigned short xs[32 * 136];   // padded: 272B rows -> 2-way max
    __shared__ __align__(16) float gbuf[32 * 132];
    const int tid = threadIdx.x;
    const int i0 = blockIdx.x * 32;
    const int w = tid >> 6, lane = tid & 63;
    const int wr = w >> 1, wc = w & 1;
    const int lr = lane & 15, lk = lane >> 4;
    const unsigned short* wt = wc ? wgt : wfct;

    floatx4 acc[8];
#pragma unroll
    for (int n = 0; n < 8; ++n) acc[n] = (floatx4)0.0f;

    const int srow = tid >> 3, se = tid & 7;
    for (int kc = 0; kc < 8; ++kc) {
        // stage x chunk [32][128] fp32 -> bf16 LDS
        {
            const float* gp = x + (size_t)(i0 + srow) * 1024 + kc * 128 + se * 16;
            unsigned short* lp = xs + srow * 136 + se * 16;
#pragma unroll
            for (int f = 0; f < 4; ++f) {
                float4 v = *(const float4*)(gp + f * 4);
                ushortx4 b;
                b.x = f2bf(v.x); b.y = f2bf(v.y); b.z = f2bf(v.z); b.w = f2bf(v.w);
                *(ushortx4*)(lp + f * 4) = b;
            }
        }
        __syncthreads();
#pragma unroll
        for (int ks = 0; ks < 4; ++ks) {
            short8 a = *(const short8*)(xs + (wr * 16 + lr) * 136 + ks * 32 + lk * 8);
#pragma unroll
            for (int n = 0; n < 8; ++n) {
                short8 b = *(const short8*)(wt + (size_t)(n * 16 + lr) * 1024 + kc * 128 + ks * 32 + lk * 8);
                acc[n] = MFMA16(a, b, acc[n]);
            }
        }
        __syncthreads();
    }
    // epilogue: gate waves -> sigmoid -> LDS; fc waves -> h -> global
    if (wc == 1) {
#pragma unroll
        for (int n = 0; n < 8; ++n) {
            int col = n * 16 + lr;
            float bb = bg[col];
#pragma unroll
            for (int r = 0; r < 4; ++r) {
                float v = acc[n][r] + bb;
                float s = __builtin_amdgcn_rcpf(1.0f + __builtin_amdgcn_exp2f(-1.4426950408889634f * v));
                gbuf[(wr * 16 + lk * 4 + r) * 132 + col] = s;
            }
        }
    }
    __syncthreads();
    if (wc == 0) {
#pragma unroll
        for (int n = 0; n < 8; ++n) {
            int col = n * 16 + lr;
            float bb = bfc[col];
#pragma unroll
            for (int r = 0; r < 4; ++r) {
                int row = wr * 16 + lk * 4 + r;
                float v = (acc[n][r] + bb) * gbuf[row * 132 + col];
                h[(size_t)(i0 + row) * 128 + col] = f2bf(v);
            }
        }
    }
}

// ---------- K3: q,k,v = h @ {W_q,W_k,W_v} + b;  q *= QSCALE; v stored transposed ----------
// grid 256 x 256 thr; block = 32 rows; wave(wr,wc): rows wr*16..+16, cols wc*192..+192 of [q|k|v]
__global__ __launch_bounds__(256) void k_qkv(const unsigned short* __restrict__ h,
                                             const unsigned short* __restrict__ wqt,
                                             const unsigned short* __restrict__ wkt,
                                             const unsigned short* __restrict__ wvt,
                                             const float* __restrict__ bq,
                                             const float* __restrict__ bk,
                                             const float* __restrict__ bv,
                                             unsigned short* __restrict__ q,
                                             unsigned short* __restrict__ kt,
                                             unsigned short* __restrict__ vt) {
    __shared__ __align__(16) unsigned short hs[32 * 136];
    const int tid = threadIdx.x;
    const int i0 = blockIdx.x * 32;
    const int w = tid >> 6, lane = tid & 63;
    const int wr = w >> 1, wc = w & 1;
    const int lr = lane & 15, lk = lane >> 4;

    {   // stage h tile [32][128] bf16
        const int srow = tid >> 3, se = tid & 7;
        const unsigned short* gp = h + (size_t)(i0 + srow) * 128 + se * 16;
        unsigned short* lp = hs + srow * 136 + se * 16;
        *(short8*)(lp) = *(const short8*)(gp);
        *(short8*)(lp + 8) = *(const short8*)(gp + 8);
    }
    __syncthreads();

    const unsigned short* wts[3] = {wqt, wkt, wvt};
    floatx4 acc[12];
#pragma unroll
    for (int n = 0; n < 12; ++n) acc[n] = (floatx4)0.0f;

#pragma unroll
    for (int ks = 0; ks < 4; ++ks) {
        short8 a = *(const short8*)(hs + (wr * 16 + lr) * 136 + ks * 32 + lk * 8);
#pragma unroll
        for (int n = 0; n < 12; ++n) {
            int gn = wc * 192 + n * 16;
            int tt = gn >> 7, cn0 = gn & 127;
            short8 b = *(const short8*)(wts[tt] + (size_t)(cn0 + lr) * 128 + ks * 32 + lk * 8);
            acc[n] = MFMA16(a, b, acc[n]);
        }
    }

    const float* bss[3] = {bq, bk, bv};
#pragma unroll
    for (int n = 0; n < 12; ++n) {
        int gn = wc * 192 + n * 16;
        int tt = gn >> 7, cn0 = gn & 127;
        int col = cn0 + lr;
        float bb = bss[tt][col];
        if (tt == 2) {
            ushortx4 pv;
#pragma unroll
            for (int r = 0; r < 4; ++r) pv[r] = f2bf(acc[n][r] + bb);
            *(ushortx4*)(vt + (size_t)col * 8192 + i0 + wr * 16 + lk * 4) = pv;
        } else {
            float sc = (tt == 0) ? QSCALE : 1.0f;
            unsigned short* dst = (tt == 0) ? q : kt;
#pragma unroll
            for (int r = 0; r < 4; ++r)
                dst[(size_t)(i0 + wr * 16 + lk * 4 + r) * 128 + col] = f2bf((acc[n][r] + bb) * sc);
        }
    }
}

// ---------- K4: flash attention, no-max online softmax, split-J partials ----------
// grid (64, nsplit) x 256 thr; block = 128 Q rows; wave(wr,wc): Q-rows wr*64..+64
// per 64-wide J tile: S=Q@K^T (wc = j-half 32), P=exp2(S)->LDS, O+=P@V (wc = d-half 64)
__global__ __launch_bounds__(256, 1) void k_flash(const unsigned short* __restrict__ qg,
                                                  const unsigned short* __restrict__ kg,
                                                  const unsigned short* __restrict__ vtg,
                                                  float* __restrict__ op,
                                                  float* __restrict__ lp,
                                                  int jrange) {
    __shared__ __align__(16) unsigned short Ks[64 * 136];   // K tile, 272B rows (padded)
    __shared__ __align__(16) unsigned short Vs[128 * 72];   // V^T tile, 144B rows
    __shared__ __align__(16) unsigned short Ps[128 * 72];   // P tile, 144B rows
    const int tid = threadIdx.x;
    const int i0 = blockIdx.x * 128;
    const int w = tid >> 6, lane = tid & 63;
    const int wr = w >> 1, wc = w & 1;
    const int lr = lane & 15, lk = lane >> 4;

    // Q fragments live in registers for the whole kernel (64 VGPRs)
    short8 qf[4][4];
#pragma unroll
    for (int mt = 0; mt < 4; ++mt)
#pragma unroll
        for (int ks = 0; ks < 4; ++ks)
            qf[mt][ks] = *(const short8*)(qg + (size_t)(i0 + wr * 64 + mt * 16 + lr) * 128 + ks * 32 + lk * 8);

    floatx4 acc_o[4][4];
    floatx4 lpart[4];
#pragma unroll
    for (int mt = 0; mt < 4; ++mt) {
        lpart[mt] = (floatx4)0.0f;
#pragma unroll
        for (int nt = 0; nt < 4; ++nt) acc_o[mt][nt] = (floatx4)0.0f;
    }

    const int jbase = blockIdx.y * jrange;
    const int ntile = jrange >> 6;
    const int krow = tid >> 2, kq = tid & 3;   // K staging: 64 rows x 4 chunks
    const int vrow = tid >> 1, vh = tid & 1;   // V^T staging: 128 rows x 2 halves

    for (int jt = 0; jt < ntile; ++jt) {
        const int j0 = jbase + jt * 64;
        {   // stage K tile [64][128]
            const unsigned short* gp = kg + (size_t)(j0 + krow) * 128 + kq * 32;
            unsigned short* lpK = Ks + krow * 136 + kq * 32;
#pragma unroll
            for (int i = 0; i < 4; ++i) *(short8*)(lpK + i * 8) = *(const short8*)(gp + i * 8);
        }
        {   // stage V^T tile [128][64]
            const unsigned short* gp = vtg + (size_t)vrow * 8192 + j0 + vh * 32;
            unsigned short* lpV = Vs + vrow * 72 + vh * 32;
#pragma unroll
            for (int i = 0; i < 4; ++i) *(short8*)(lpV + i * 8) = *(const short8*)(gp + i * 8);
        }
        __syncthreads();

        // S = Qs @ K^T   (wave: 64 rows x 32 j-cols)
        floatx4 accs[4][2];
#pragma unroll
        for (int mt = 0; mt < 4; ++mt) { accs[mt][0] = (floatx4)0.0f; accs[mt][1] = (floatx4)0.0f; }
#pragma unroll
        for (int ks = 0; ks < 4; ++ks) {
            short8 b0 = *(const short8*)(Ks + (wc * 32 + lr) * 136 + ks * 32 + lk * 8);
            short8 b1 = *(const short8*)(Ks + (wc * 32 + 16 + lr) * 136 + ks * 32 + lk * 8);
#pragma unroll
            for (int mt = 0; mt < 4; ++mt) {
                accs[mt][0] = MFMA16(qf[mt][ks], b0, accs[mt][0]);
                accs[mt][1] = MFMA16(qf[mt][ks], b1, accs[mt][1]);
            }
        }
        // P = exp2(S); accumulate row-sums; write P to LDS (C-layout -> A-layout via LDS)
#pragma unroll
        for (int mt = 0; mt < 4; ++mt)
#pragma unroll
            for (int nt = 0; nt < 2; ++nt)
#pragma unroll
                for (int r = 0; r < 4; ++r) {
                    float p = __builtin_amdgcn_exp2f(accs[mt][nt][r]);
                    lpart[mt][r] += p;
                    Ps[(wr * 64 + mt * 16 + lk * 4 + r) * 72 + wc * 32 + nt * 16 + lr] = f2bf(p);
                }
        __syncthreads();

        // O += P @ V   (wave: 64 rows x 64 d-cols)
#pragma unroll
        for (int ks = 0; ks < 2; ++ks) {
            short8 pa[4], vb[4];
#pragma unroll
            for (int mt = 0; mt < 4; ++mt)
                pa[mt] = *(const short8*)(Ps + (wr * 64 + mt * 16 + lr) * 72 + ks * 32 + lk * 8);
#pragma unroll
            for (int nt = 0; nt < 4; ++nt)
                vb[nt] = *(const short8*)(Vs + (wc * 64 + nt * 16 + lr) * 72 + ks * 32 + lk * 8);
#pragma unroll
            for (int mt = 0; mt < 4; ++mt)
#pragma unroll
                for (int nt = 0; nt < 4; ++nt)
                    acc_o[mt][nt] = MFMA16(pa[mt], vb[nt], acc_o[mt][nt]);
        }
        __syncthreads();
    }

    // l partials: reduce over the 16 col-lanes, store per (split, wc)
#pragma unroll
    for (int mt = 0; mt < 4; ++mt) {
        floatx4 v = lpart[mt];
#pragma unroll
        for (int d = 1; d < 16; d <<= 1) {
            floatx4 o;
            o[0] = __shfl_xor(v[0], d); o[1] = __shfl_xor(v[1], d);
            o[2] = __shfl_xor(v[2], d); o[3] = __shfl_xor(v[3], d);
            v += o;
        }
        if (lr == 0)
            *(floatx4*)(lp + (size_t)(blockIdx.y * 2 + wc) * 8192 + i0 + wr * 64 + mt * 16 + lk * 4) = v;
    }
    // O partials
    float* obase = op + ((size_t)blockIdx.y << 20);
#pragma unroll
    for (int mt = 0; mt < 4; ++mt)
#pragma unroll
        for (int nt = 0; nt < 4; ++nt)
#pragma unroll
            for (int r = 0; r < 4; ++r)
                obase[(size_t)(i0 + wr * 64 + mt * 16 + lk * 4 + r) * 128 + wc * 64 + nt * 16 + lr] = acc_o[mt][nt][r];
}

// ---------- K5: out = ((sum_s O_s) / (sum l)) @ W_out + b_out ----------
__global__ __launch_bounds__(256) void k_out(const float* __restrict__ op,
                                             const float* __restrict__ lp,
                                             const float* __restrict__ wout,
                                             const float* __restrict__ bout,
                                             float* __restrict__ out, int nsplit) {
    const int tid = threadIdx.x;
    const int w = tid >> 6, lane = tid & 63;
    const int base = blockIdx.x * 16 + w * 4;
    float w1 = wout[lane], w2 = wout[lane + 64];
    for (int i = 0; i < 4; ++i) {
        int row = base + i;
        float o1 = 0.f, o2 = 0.f;
        for (int s = 0; s < nsplit; ++s) {
            const float* p = op + ((size_t)s << 20) + (size_t)row * 128;
            o1 += p[lane]; o2 += p[lane + 64];
        }
        float l = 0.f;
        for (int t = 0; t < 2 * nsplit; ++t) l += lp[(size_t)t * 8192 + row];
        float val = o1 * w1 + o2 * w2;
#pragma unroll
        for (int d = 1; d < 64; d <<= 1) val += __shfl_xor(val, d);
        if (lane == 0) out[row] = val / l + bout[0];
    }
}

// ---------- launch ----------
extern "C" void kernel_launch(void* const* d_in, const int* in_sizes, int n_in,
                              void* d_out, int out_size, void* d_ws, size_t ws_size,
                              hipStream_t stream) {
    const float* x    = (const float*)d_in[0];
    const float* Wfc  = (const float*)d_in[1];
    const float* bfc  = (const float*)d_in[2];
    const float* Wg   = (const float*)d_in[3];
    const float* bg   = (const float*)d_in[4];
    const float* Wq   = (const float*)d_in[5];
    const float* bq   = (const float*)d_in[6];
    const float* Wk   = (const float*)d_in[7];
    const float* bk   = (const float*)d_in[8];
    const float* Wv   = (const float*)d_in[9];
    const float* bv   = (const float*)d_in[10];
    const float* Wout = (const float*)d_in[11];
    const float* bout = (const float*)d_in[12];
    char* ws = (char*)d_ws;

    unsigned short* h    = (unsigned short*)(ws + H_OFF);
    unsigned short* qb   = (unsigned short*)(ws + Q_OFF);
    unsigned short* kb   = (unsigned short*)(ws + K_OFF);
    unsigned short* vtb  = (unsigned short*)(ws + VT_OFF);
    unsigned short* wfct = (unsigned short*)(ws + WFCT_OFF);
    unsigned short* wgt  = (unsigned short*)(ws + WGT_OFF);
    unsigned short* wqt  = (unsigned short*)(ws + WQT_OFF);
    unsigned short* wkt  = (unsigned short*)(ws + WKT_OFF);
    unsigned short* wvt  = (unsigned short*)(ws + WVT_OFF);
    float* lpb = (float*)(ws + LP_OFF);
    float* opb = (float*)(ws + OP_OFF);

    int nsplit = 1;
    if (ws_size >= OP_OFF + ((size_t)8 << 22)) nsplit = 8;
    else if (ws_size >= OP_OFF + ((size_t)4 << 22)) nsplit = 4;
    else if (ws_size >= OP_OFF + ((size_t)2 << 22)) nsplit = 2;

    k_transw<<<512, 256, 0, stream>>>(Wfc, wfct, 1024, 128);
    k_transw<<<512, 256, 0, stream>>>(Wg, wgt, 1024, 128);
    k_transw<<<64, 256, 0, stream>>>(Wq, wqt, 128, 128);
    k_transw<<<64, 256, 0, stream>>>(Wk, wkt, 128, 128);
    k_transw<<<64, 256, 0, stream>>>(Wv, wvt, 128, 128);

    k_gated<<<256, 256, 0, stream>>>(x, wfct, wgt, bfc, bg, h);
    k_qkv<<<256, 256, 0, stream>>>(h, wqt, wkt, wvt, bq, bk, bv, qb, kb, vtb);

    dim3 gf(64, nsplit);
    k_flash<<<gf, 256, 0, stream>>>(qb, kb, vtb, opb, lpb, 8192 / nsplit);

    k_out<<<512, 256, 0, stream>>>(opb, lpb, Wout, bout, (float*)d_out, nsplit);
}

// Round 2
// 182.812 us; speedup vs baseline: 1.5103x; 1.5103x over previous
//
#include <hip/hip_runtime.h>

// ---------- types ----------
typedef short short8 __attribute__((ext_vector_type(8)));        // 8 bf16 (4 VGPRs) MFMA A/B frag
typedef float floatx4 __attribute__((ext_vector_type(4)));       // MFMA C/D frag
typedef unsigned short ushortx4 __attribute__((ext_vector_type(4)));

__device__ __forceinline__ unsigned short f2bf(float f) {
    unsigned u = __float_as_uint(f);
    u += 0x7fffu + ((u >> 16) & 1u);   // RNE
    return (unsigned short)(u >> 16);
}
__device__ __forceinline__ unsigned packbf(float a, float b) {
    return (unsigned)f2bf(a) | ((unsigned)f2bf(b) << 16);
}

#define MFMA16(a, b, c) __builtin_amdgcn_mfma_f32_16x16x32_bf16((a), (b), (c), 0, 0, 0)

// ---------- ws layout (bytes) ----------
static constexpr size_t Q_OFF    = 2097152;           // q*scale bf16 [8192][128]
static constexpr size_t K_OFF    = 4194304;           // k bf16 [8192][128]
static constexpr size_t VT_OFF   = 6291456;           // v^T bf16 [128][8192]
static constexpr size_t WFCT_OFF = 8388608;           // W_fc^T bf16 [128][1024]
static constexpr size_t WGT_OFF  = 8650752;           // W_gate^T bf16 [128][1024]
static constexpr size_t WQT_OFF  = 8912896;           // W_q^T bf16 [128][128]
static constexpr size_t WKT_OFF  = 8945664;
static constexpr size_t WVT_OFF  = 8978432;
static constexpr size_t LP_OFF   = 9011200;           // l partials fp32 [nsplit][8192]
static constexpr size_t OP_OFF   = 9535488;           // O partials fp32 [nsplit][8192][128]

// log2(e)/sqrt(128): folded into stored q so P = exp2(S)
static constexpr float QSCALE = 0.1275174308f;

// ---------- K1: all weight transposes + fp32->bf16, one launch ----------
__global__ void k_transw_all(const float* __restrict__ wfc, const float* __restrict__ wg,
                             const float* __restrict__ wq, const float* __restrict__ wk,
                             const float* __restrict__ wv,
                             unsigned short* __restrict__ dfc, unsigned short* __restrict__ dg,
                             unsigned short* __restrict__ dq, unsigned short* __restrict__ dk,
                             unsigned short* __restrict__ dv) {
    int i = blockIdx.x * 256 + threadIdx.x;
    const float* s; unsigned short* d; int K, base;
    if (i < 131072)      { s = wfc; d = dfc; K = 1024; base = 0; }
    else if (i < 262144) { s = wg;  d = dg;  K = 1024; base = 131072; }
    else if (i < 278528) { s = wq;  d = dq;  K = 128;  base = 262144; }
    else if (i < 294912) { s = wk;  d = dk;  K = 128;  base = 278528; }
    else if (i < 311296) { s = wv;  d = dv;  K = 128;  base = 294912; }
    else return;
    int j = i - base;
    int kk = j >> 7, nn = j & 127;   // all matrices have 128 output cols
    d[nn * K + kk] = f2bf(s[j]);
}

// ---------- K2: fused gated-linear + QKV ----------
// grid 256 x 512 thr; block = 32 rows.
// Phase A: h = (x@W_fc+b)*sigmoid(x@W_gate+b) -> LDS only.  8 waves: w<4 fc cols w*32, w>=4 gate cols (w-4)*32.
// Phase B: q,k,v = h@W + b from LDS h; q*=QSCALE; v stored transposed. wave w -> cols w*48 of [q|k|v].
__global__ __launch_bounds__(512) void k_gq(const float* __restrict__ x,
                                            const unsigned short* __restrict__ wfct,
                                            const unsigned short* __restrict__ wgt,
                                            const float* __restrict__ bfc,
                                            const float* __restrict__ bg,
                                            const unsigned short* __restrict__ wqt,
                                            const unsigned short* __restrict__ wkt,
                                            const unsigned short* __restrict__ wvt,
                                            const float* __restrict__ bq,
                                            const float* __restrict__ bk,
                                            const float* __restrict__ bv,
                                            unsigned short* __restrict__ q,
                                            unsigned short* __restrict__ kt,
                                            unsigned short* __restrict__ vt) {
    __shared__ __align__(16) unsigned short xs[32 * 136];
    __shared__ __align__(16) float gbuf[32 * 132];
    __shared__ __align__(16) unsigned short hs[32 * 136];
    const int tid = threadIdx.x;
    const int i0 = blockIdx.x * 32;
    const int w = tid >> 6, lane = tid & 63;
    const int lr = lane & 15, lk = lane >> 4;

    const int isg = (w >= 4);
    const int ncol0 = (w & 3) * 32;
    const unsigned short* wt = isg ? wgt : wfct;

    floatx4 acc[2][2];
#pragma unroll
    for (int mt = 0; mt < 2; ++mt)
#pragma unroll
        for (int nt = 0; nt < 2; ++nt) acc[mt][nt] = (floatx4)0.0f;

    const int srow = tid >> 4, se = tid & 15;
    for (int kc = 0; kc < 8; ++kc) {
        {   // stage x [32][128] fp32 -> bf16
            const float* gp = x + (size_t)(i0 + srow) * 1024 + kc * 128 + se * 8;
            float4 v0 = *(const float4*)gp;
            float4 v1 = *(const float4*)(gp + 4);
            short8 t;
            unsigned short* tp = (unsigned short*)&t;
            tp[0] = f2bf(v0.x); tp[1] = f2bf(v0.y); tp[2] = f2bf(v0.z); tp[3] = f2bf(v0.w);
            tp[4] = f2bf(v1.x); tp[5] = f2bf(v1.y); tp[6] = f2bf(v1.z); tp[7] = f2bf(v1.w);
            *(short8*)(xs + srow * 136 + se * 8) = t;
        }
        __syncthreads();
#pragma unroll
        for (int ks = 0; ks < 4; ++ks) {
            short8 a[2], b[2];
#pragma unroll
            for (int mt = 0; mt < 2; ++mt)
                a[mt] = *(const short8*)(xs + (mt * 16 + lr) * 136 + ks * 32 + lk * 8);
#pragma unroll
            for (int nt = 0; nt < 2; ++nt)
                b[nt] = *(const short8*)(wt + (size_t)(ncol0 + nt * 16 + lr) * 1024 + kc * 128 + ks * 32 + lk * 8);
#pragma unroll
            for (int mt = 0; mt < 2; ++mt)
#pragma unroll
                for (int nt = 0; nt < 2; ++nt)
                    acc[mt][nt] = MFMA16(a[mt], b[nt], acc[mt][nt]);
        }
        __syncthreads();
    }
    // epilogue A
    if (isg) {
#pragma unroll
        for (int mt = 0; mt < 2; ++mt)
#pragma unroll
            for (int nt = 0; nt < 2; ++nt) {
                int col = ncol0 + nt * 16 + lr;
                float bb = bg[col];
#pragma unroll
                for (int r = 0; r < 4; ++r) {
                    float v = acc[mt][nt][r] + bb;
                    gbuf[(mt * 16 + lk * 4 + r) * 132 + col] =
                        __builtin_amdgcn_rcpf(1.0f + __builtin_amdgcn_exp2f(-1.4426950408889634f * v));
                }
            }
    }
    __syncthreads();
    if (!isg) {
#pragma unroll
        for (int mt = 0; mt < 2; ++mt)
#pragma unroll
            for (int nt = 0; nt < 2; ++nt) {
                int col = ncol0 + nt * 16 + lr;
                float bb = bfc[col];
#pragma unroll
                for (int r = 0; r < 4; ++r) {
                    int row = mt * 16 + lk * 4 + r;
                    hs[row * 136 + col] = f2bf((acc[mt][nt][r] + bb) * gbuf[row * 132 + col]);
                }
            }
    }
    __syncthreads();

    // Phase B
    const unsigned short* wts[3] = {wqt, wkt, wvt};
    floatx4 qacc[2][3];
#pragma unroll
    for (int mt = 0; mt < 2; ++mt)
#pragma unroll
        for (int nt = 0; nt < 3; ++nt) qacc[mt][nt] = (floatx4)0.0f;

#pragma unroll
    for (int ks = 0; ks < 4; ++ks) {
        short8 a[2];
#pragma unroll
        for (int mt = 0; mt < 2; ++mt)
            a[mt] = *(const short8*)(hs + (mt * 16 + lr) * 136 + ks * 32 + lk * 8);
#pragma unroll
        for (int nt = 0; nt < 3; ++nt) {
            int c = w * 48 + nt * 16;
            int tt = c >> 7, cc = c & 127;
            short8 b = *(const short8*)(wts[tt] + (size_t)(cc + lr) * 128 + ks * 32 + lk * 8);
#pragma unroll
            for (int mt = 0; mt < 2; ++mt)
                qacc[mt][nt] = MFMA16(a[mt], b, qacc[mt][nt]);
        }
    }
    const float* bss[3] = {bq, bk, bv};
#pragma unroll
    for (int nt = 0; nt < 3; ++nt) {
        int c = w * 48 + nt * 16;
        int tt = c >> 7, cc = c & 127;
        int col = cc + lr;
        float bb = bss[tt][col];
        if (tt == 2) {
#pragma unroll
            for (int mt = 0; mt < 2; ++mt) {
                ushortx4 pv;
#pragma unroll
                for (int r = 0; r < 4; ++r) pv[r] = f2bf(qacc[mt][nt][r] + bb);
                *(ushortx4*)(vt + (size_t)col * 8192 + i0 + mt * 16 + lk * 4) = pv;
            }
        } else {
            float sc = (tt == 0) ? QSCALE : 1.0f;
            unsigned short* dst = (tt == 0) ? q : kt;
#pragma unroll
            for (int mt = 0; mt < 2; ++mt)
#pragma unroll
                for (int r = 0; r < 4; ++r)
                    dst[(size_t)(i0 + mt * 16 + lk * 4 + r) * 128 + col] = f2bf((qacc[mt][nt][r] + bb) * sc);
        }
    }
}

// ---------- K3: flash attention v2 ----------
// grid (32, nsplit) x 512 thr; block = 256 Q rows, 8 waves, wave w owns q-rows w*32..+32.
// Per 64-j tile: S^T = K@Q^T (C-layout gives j-consecutive elems per lane -> b64 P^T writes into
// wave-PRIVATE Pt rows), then O += P@V reading only own Pt rows + shared Vs. K/V double-buffered,
// staging issued right after the single barrier -> overlaps all compute.
static constexpr int KS0 = 0;          // [64][136]
static constexpr int KS1 = 8704;
static constexpr int VS0 = 17408;      // [128][72]
static constexpr int VS1 = 26624;
static constexpr int PT0 = 35840;      // [256][72]
__global__ __launch_bounds__(512, 2) void k_flash(const unsigned short* __restrict__ qg,
                                                  const unsigned short* __restrict__ kg,
                                                  const unsigned short* __restrict__ vtg,
                                                  float* __restrict__ op,
                                                  float* __restrict__ lp,
                                                  int jrange) {
    __shared__ __align__(16) unsigned short lds[54272];   // 108.5 KB
    const int tid = threadIdx.x;
    const int i0 = blockIdx.x * 256;
    const int w = tid >> 6, lane = tid & 63;
    const int lr = lane & 15, lk = lane >> 4;

    // Q fragments in registers for whole kernel: rows w*32..+32
    short8 qf[2][4];
#pragma unroll
    for (int mt = 0; mt < 2; ++mt)
#pragma unroll
        for (int ks = 0; ks < 4; ++ks)
            qf[mt][ks] = *(const short8*)(qg + (size_t)(i0 + w * 32 + mt * 16 + lr) * 128 + ks * 32 + lk * 8);

    floatx4 oacc[2][8];
    float lsum[2] = {0.f, 0.f};
#pragma unroll
    for (int mt = 0; mt < 2; ++mt)
#pragma unroll
        for (int dt = 0; dt < 8; ++dt) oacc[mt][dt] = (floatx4)0.0f;

    const int jbase = blockIdx.y * jrange;
    const int ntile = jrange >> 6;
    const int krow = tid >> 3, kc8 = (tid & 7) << 4;   // K: 64 rows, 8 thr/row, 16 shorts
    const int vrow = tid >> 2, vc4 = (tid & 3) << 4;   // V^T: 128 rows, 4 thr/row, 16 shorts

    auto stage = [&](int j0, int buf) {
        const unsigned short* gk = kg + (size_t)(j0 + krow) * 128 + kc8;
        const unsigned short* gv = vtg + (size_t)vrow * 8192 + j0 + vc4;
        short8 t0 = *(const short8*)gk;
        short8 t1 = *(const short8*)(gk + 8);
        short8 t2 = *(const short8*)gv;
        short8 t3 = *(const short8*)(gv + 8);
        unsigned short* dk = lds + (buf ? KS1 : KS0) + krow * 136 + kc8;
        unsigned short* dv = lds + (buf ? VS1 : VS0) + vrow * 72 + vc4;
        *(short8*)dk = t0;
        *(short8*)(dk + 8) = t1;
        *(short8*)dv = t2;
        *(short8*)(dv + 8) = t3;
    };

    stage(jbase, 0);
    for (int jt = 0; jt < ntile; ++jt) {
        __syncthreads();                                     // staging of cur done; prev compute done
        if (jt + 1 < ntile) stage(jbase + (jt + 1) * 64, (jt + 1) & 1);   // overlapped prefetch

        const unsigned short* Kb = lds + ((jt & 1) ? KS1 : KS0);
        const unsigned short* Vb = lds + ((jt & 1) ? VS1 : VS0);

        // S^T = K @ Q^T : rows j (64), cols m (this wave's 32)
        floatx4 sacc[4][2];
#pragma unroll
        for (int j4 = 0; j4 < 4; ++j4) { sacc[j4][0] = (floatx4)0.0f; sacc[j4][1] = (floatx4)0.0f; }
#pragma unroll
        for (int ks = 0; ks < 4; ++ks) {
            short8 af[4];
#pragma unroll
            for (int j4 = 0; j4 < 4; ++j4)
                af[j4] = *(const short8*)(Kb + (j4 * 16 + lr) * 136 + ks * 32 + lk * 8);
#pragma unroll
            for (int j4 = 0; j4 < 4; ++j4)
#pragma unroll
                for (int mt = 0; mt < 2; ++mt)
                    sacc[j4][mt] = MFMA16(af[j4], qf[mt][ks], sacc[j4][mt]);
        }
        // P = exp2(S): lane holds 4 consecutive j for q-row (w*32+mt*16+lr) -> b64 writes, wave-private Pt
#pragma unroll
        for (int mt = 0; mt < 2; ++mt) {
            unsigned short* prow = lds + PT0 + (w * 32 + mt * 16 + lr) * 72;
            float ls = 0.f;
#pragma unroll
            for (int j4 = 0; j4 < 4; ++j4) {
                float p0 = __builtin_amdgcn_exp2f(sacc[j4][mt][0]);
                float p1 = __builtin_amdgcn_exp2f(sacc[j4][mt][1]);
                float p2 = __builtin_amdgcn_exp2f(sacc[j4][mt][2]);
                float p3 = __builtin_amdgcn_exp2f(sacc[j4][mt][3]);
                ls += (p0 + p1) + (p2 + p3);
                uint2 pk;
                pk.x = packbf(p0, p1);
                pk.y = packbf(p2, p3);
                *(uint2*)(prow + j4 * 16 + lk * 4) = pk;
            }
            lsum[mt] += ls;
        }
        // O += P @ V  (reads only this wave's Pt rows + shared Vs; no barrier needed)
#pragma unroll
        for (int k2 = 0; k2 < 2; ++k2) {
            short8 pa[2], vb[8];
#pragma unroll
            for (int mt = 0; mt < 2; ++mt)
                pa[mt] = *(const short8*)(lds + PT0 + (w * 32 + mt * 16 + lr) * 72 + k2 * 32 + lk * 8);
#pragma unroll
            for (int dt = 0; dt < 8; ++dt)
                vb[dt] = *(const short8*)(Vb + (dt * 16 + lr) * 72 + k2 * 32 + lk * 8);
#pragma unroll
            for (int mt = 0; mt < 2; ++mt)
#pragma unroll
                for (int dt = 0; dt < 8; ++dt)
                    oacc[mt][dt] = MFMA16(pa[mt], vb[dt], oacc[mt][dt]);
        }
    }

    // l partials: reduce over lk quads (lane bits 4,5)
#pragma unroll
    for (int mt = 0; mt < 2; ++mt) {
        float v = lsum[mt];
        v += __shfl_xor(v, 16);
        v += __shfl_xor(v, 32);
        if (lk == 0)
            lp[(size_t)blockIdx.y * 8192 + i0 + w * 32 + mt * 16 + lr] = v;
    }
    // O partials
    float* obase = op + ((size_t)blockIdx.y << 20);
#pragma unroll
    for (int mt = 0; mt < 2; ++mt)
#pragma unroll
        for (int dt = 0; dt < 8; ++dt)
#pragma unroll
            for (int r = 0; r < 4; ++r)
                obase[(size_t)(i0 + w * 32 + mt * 16 + lk * 4 + r) * 128 + dt * 16 + lr] = oacc[mt][dt][r];
}

// ---------- K4: out = ((sum_s O_s) / (sum_s l_s)) @ W_out + b_out ----------
__global__ __launch_bounds__(256) void k_out(const float* __restrict__ op,
                                             const float* __restrict__ lp,
                                             const float* __restrict__ wout,
                                             const float* __restrict__ bout,
                                             float* __restrict__ out, int nsplit) {
    const int tid = threadIdx.x;
    const int w = tid >> 6, lane = tid & 63;
    const int base = blockIdx.x * 16 + w * 4;
    float w1 = wout[lane], w2 = wout[lane + 64];
    for (int i = 0; i < 4; ++i) {
        int row = base + i;
        float o1 = 0.f, o2 = 0.f;
        for (int s = 0; s < nsplit; ++s) {
            const float* p = op + ((size_t)s << 20) + (size_t)row * 128;
            o1 += p[lane]; o2 += p[lane + 64];
        }
        float l = 0.f;
        for (int t = 0; t < nsplit; ++t) l += lp[(size_t)t * 8192 + row];
        float val = o1 * w1 + o2 * w2;
#pragma unroll
        for (int d = 1; d < 64; d <<= 1) val += __shfl_xor(val, d);
        if (lane == 0) out[row] = val / l + bout[0];
    }
}

// ---------- launch ----------
extern "C" void kernel_launch(void* const* d_in, const int* in_sizes, int n_in,
                              void* d_out, int out_size, void* d_ws, size_t ws_size,
                              hipStream_t stream) {
    const float* x    = (const float*)d_in[0];
    const float* Wfc  = (const float*)d_in[1];
    const float* bfc  = (const float*)d_in[2];
    const float* Wg   = (const float*)d_in[3];
    const float* bg   = (const float*)d_in[4];
    const float* Wq   = (const float*)d_in[5];
    const float* bq   = (const float*)d_in[6];
    const float* Wk   = (const float*)d_in[7];
    const float* bk   = (const float*)d_in[8];
    const float* Wv   = (const float*)d_in[9];
    const float* bv   = (const float*)d_in[10];
    const float* Wout = (const float*)d_in[11];
    const float* bout = (const float*)d_in[12];
    char* ws = (char*)d_ws;

    unsigned short* qb   = (unsigned short*)(ws + Q_OFF);
    unsigned short* kb   = (unsigned short*)(ws + K_OFF);
    unsigned short* vtb  = (unsigned short*)(ws + VT_OFF);
    unsigned short* wfct = (unsigned short*)(ws + WFCT_OFF);
    unsigned short* wgt  = (unsigned short*)(ws + WGT_OFF);
    unsigned short* wqt  = (unsigned short*)(ws + WQT_OFF);
    unsigned short* wkt  = (unsigned short*)(ws + WKT_OFF);
    unsigned short* wvt  = (unsigned short*)(ws + WVT_OFF);
    float* lpb = (float*)(ws + LP_OFF);
    float* opb = (float*)(ws + OP_OFF);

    int nsplit = 1;
    if (ws_size >= OP_OFF + ((size_t)8 << 22)) nsplit = 8;
    else if (ws_size >= OP_OFF + ((size_t)4 << 22)) nsplit = 4;
    else if (ws_size >= OP_OFF + ((size_t)2 << 22)) nsplit = 2;

    k_transw_all<<<1216, 256, 0, stream>>>(Wfc, Wg, Wq, Wk, Wv, wfct, wgt, wqt, wkt, wvt);
    k_gq<<<256, 512, 0, stream>>>(x, wfct, wgt, bfc, bg, wqt, wkt, wvt, bq, bk, bv, qb, kb, vtb);

    dim3 gf(32, nsplit);
    k_flash<<<gf, 512, 0, stream>>>(qb, kb, vtb, opb, lpb, 8192 / nsplit);

    k_out<<<512, 256, 0, stream>>>(opb, lpb, Wout, bout, (float*)d_out, nsplit);
}

// Round 4
// 176.832 us; speedup vs baseline: 1.5614x; 1.0338x over previous
//
#include <hip/hip_runtime.h>

// ---------- types ----------
typedef short short8 __attribute__((ext_vector_type(8)));        // 8 bf16 MFMA A/B frag
typedef float floatx4 __attribute__((ext_vector_type(4)));       // MFMA C/D frag
typedef unsigned short ushortx4 __attribute__((ext_vector_type(4)));

__device__ __forceinline__ unsigned short f2bf(float f) {
    unsigned u = __float_as_uint(f);
    u += 0x7fffu + ((u >> 16) & 1u);   // RNE
    return (unsigned short)(u >> 16);
}
__device__ __forceinline__ unsigned packbf(float a, float b) {
    return (unsigned)f2bf(a) | ((unsigned)f2bf(b) << 16);
}

#define MFMA16(a, b, c)  __builtin_amdgcn_mfma_f32_16x16x32_bf16((a), (b), (c), 0, 0, 0)

// ---------- ws layout (bytes) ----------
static constexpr size_t Q_OFF    = 0;                    // q*QSCALE bf16 [8192][128]  2 MB
static constexpr size_t K_OFF    = 2u << 20;             // k bf16 [8192][128]         2 MB
static constexpr size_t VT_OFF   = 4u << 20;             // v^T bf16 [128][8192]       2 MB
static constexpr size_t WFCT_OFF = 6u << 20;             // W_fc^T bf16 [128][1024]  256 KB
static constexpr size_t WGT_OFF  = WFCT_OFF + 262144;
static constexpr size_t WQT_OFF  = WGT_OFF + 262144;     // W_q^T bf16 [128][128] 32 KB
static constexpr size_t WKT_OFF  = WQT_OFF + 32768;
static constexpr size_t WVT_OFF  = WKT_OFF + 32768;
static constexpr size_t LP_OFF   = 7u << 20;             // l partials fp32 [nsplit][8192]
static constexpr size_t OP_OFF   = 8u << 20;             // O partials fp32 [nsplit][8192][128]

// log2(e)/sqrt(128): folded into stored q so P = exp2(S)
static constexpr float QSCALE = 0.1275174308f;

// ---------- K1: all weight transposes + fp32->bf16, one launch ----------
__global__ void k_transw_all(const float* __restrict__ wfc, const float* __restrict__ wg,
                             const float* __restrict__ wq, const float* __restrict__ wk,
                             const float* __restrict__ wv,
                             unsigned short* __restrict__ dfc, unsigned short* __restrict__ dg,
                             unsigned short* __restrict__ dq, unsigned short* __restrict__ dk,
                             unsigned short* __restrict__ dv) {
    int i = blockIdx.x * 256 + threadIdx.x;
    const float* s; unsigned short* d; int K, base;
    if (i < 131072)      { s = wfc; d = dfc; K = 1024; base = 0; }
    else if (i < 262144) { s = wg;  d = dg;  K = 1024; base = 131072; }
    else if (i < 278528) { s = wq;  d = dq;  K = 128;  base = 262144; }
    else if (i < 294912) { s = wk;  d = dk;  K = 128;  base = 278528; }
    else if (i < 311296) { s = wv;  d = dv;  K = 128;  base = 294912; }
    else return;
    int j = i - base;
    int kk = j >> 7, nn = j & 127;
    d[nn * K + kk] = f2bf(s[j]);
}

// ---------- K2: fused gated-linear + QKV (bf16 outputs) ----------
// grid 256 x 512 thr; block = 32 rows; register-prefetched x, double-buffered x LDS.
// Phase A: 8 waves, w<4 -> fc cols (w&3)*32, w>=4 -> gate. h -> LDS.
// Phase B: wave w -> cols w*48 of [q|k|v]; q pre-scaled by QSCALE; v stored transposed.
__global__ __launch_bounds__(512, 2) void k_gq(const float* __restrict__ x,
                                               const unsigned short* __restrict__ wfct,
                                               const unsigned short* __restrict__ wgt,
                                               const float* __restrict__ bfc,
                                               const float* __restrict__ bg,
                                               const unsigned short* __restrict__ wqt,
                                               const unsigned short* __restrict__ wkt,
                                               const unsigned short* __restrict__ wvt,
                                               const float* __restrict__ bq,
                                               const float* __restrict__ bk,
                                               const float* __restrict__ bv,
                                               unsigned short* __restrict__ q,
                                               unsigned short* __restrict__ kt,
                                               unsigned short* __restrict__ vt) {
    __shared__ __align__(16) unsigned short xs[2][32 * 136];
    __shared__ __align__(16) float gbuf[32 * 132];
    __shared__ __align__(16) unsigned short hs[32 * 136];
    const int tid = threadIdx.x;
    const int i0 = blockIdx.x * 32;
    const int w = tid >> 6, lane = tid & 63;
    const int lr = lane & 15, lk = lane >> 4;

    const int isg = (w >= 4);
    const int ncol0 = (w & 3) * 32;
    const unsigned short* wt = isg ? wgt : wfct;

    floatx4 acc[2][2];
#pragma unroll
    for (int mt = 0; mt < 2; ++mt)
#pragma unroll
        for (int nt = 0; nt < 2; ++nt) acc[mt][nt] = (floatx4)0.0f;

    const int srow = tid >> 4, se = tid & 15;   // 32 rows x 16 thr, 8 floats each
    const float* gp0 = x + (size_t)(i0 + srow) * 1024 + se * 8;
    float4 ra = *(const float4*)gp0;
    float4 rb = *(const float4*)(gp0 + 4);

    for (int kc = 0; kc < 8; ++kc) {
        {   // write prefetched chunk into LDS buf kc&1
            short8 t;
            unsigned short* tp = (unsigned short*)&t;
            tp[0] = f2bf(ra.x); tp[1] = f2bf(ra.y); tp[2] = f2bf(ra.z); tp[3] = f2bf(ra.w);
            tp[4] = f2bf(rb.x); tp[5] = f2bf(rb.y); tp[6] = f2bf(rb.z); tp[7] = f2bf(rb.w);
            *(short8*)(xs[kc & 1] + srow * 136 + se * 8) = t;
        }
        if (kc < 7) {   // prefetch next chunk
            const float* gp = gp0 + (kc + 1) * 128;
            ra = *(const float4*)gp;
            rb = *(const float4*)(gp + 4);
        }
        __syncthreads();
        const unsigned short* xb = xs[kc & 1];
#pragma unroll
        for (int ks = 0; ks < 4; ++ks) {
            short8 a[2], b[2];
#pragma unroll
            for (int mt = 0; mt < 2; ++mt)
                a[mt] = *(const short8*)(xb + (mt * 16 + lr) * 136 + ks * 32 + lk * 8);
#pragma unroll
            for (int nt = 0; nt < 2; ++nt)
                b[nt] = *(const short8*)(wt + (size_t)(ncol0 + nt * 16 + lr) * 1024 + kc * 128 + ks * 32 + lk * 8);
#pragma unroll
            for (int mt = 0; mt < 2; ++mt)
#pragma unroll
                for (int nt = 0; nt < 2; ++nt)
                    acc[mt][nt] = MFMA16(a[mt], b[nt], acc[mt][nt]);
        }
    }
    __syncthreads();
    // epilogue A
    if (isg) {
#pragma unroll
        for (int mt = 0; mt < 2; ++mt)
#pragma unroll
            for (int nt = 0; nt < 2; ++nt) {
                int col = ncol0 + nt * 16 + lr;
                float bb = bg[col];
#pragma unroll
                for (int r = 0; r < 4; ++r) {
                    float v = acc[mt][nt][r] + bb;
                    gbuf[(mt * 16 + lk * 4 + r) * 132 + col] =
                        __builtin_amdgcn_rcpf(1.0f + __builtin_amdgcn_exp2f(-1.4426950408889634f * v));
                }
            }
    }
    __syncthreads();
    if (!isg) {
#pragma unroll
        for (int mt = 0; mt < 2; ++mt)
#pragma unroll
            for (int nt = 0; nt < 2; ++nt) {
                int col = ncol0 + nt * 16 + lr;
                float bb = bfc[col];
#pragma unroll
                for (int r = 0; r < 4; ++r) {
                    int row = mt * 16 + lk * 4 + r;
                    hs[row * 136 + col] = f2bf((acc[mt][nt][r] + bb) * gbuf[row * 132 + col]);
                }
            }
    }
    __syncthreads();

    // Phase B: q,k,v
    const unsigned short* wts[3] = {wqt, wkt, wvt};
    floatx4 qacc[2][3];
#pragma unroll
    for (int mt = 0; mt < 2; ++mt)
#pragma unroll
        for (int nt = 0; nt < 3; ++nt) qacc[mt][nt] = (floatx4)0.0f;

#pragma unroll
    for (int ks = 0; ks < 4; ++ks) {
        short8 a[2];
#pragma unroll
        for (int mt = 0; mt < 2; ++mt)
            a[mt] = *(const short8*)(hs + (mt * 16 + lr) * 136 + ks * 32 + lk * 8);
#pragma unroll
        for (int nt = 0; nt < 3; ++nt) {
            int c = w * 48 + nt * 16;
            int tt = c >> 7, cc = c & 127;
            short8 b = *(const short8*)(wts[tt] + (size_t)(cc + lr) * 128 + ks * 32 + lk * 8);
#pragma unroll
            for (int mt = 0; mt < 2; ++mt)
                qacc[mt][nt] = MFMA16(a[mt], b, qacc[mt][nt]);
        }
    }
    const float* bss[3] = {bq, bk, bv};
#pragma unroll
    for (int nt = 0; nt < 3; ++nt) {
        int c = w * 48 + nt * 16;
        int tt = c >> 7, cc = c & 127;
        int col = cc + lr;
        float bb = bss[tt][col];
        if (tt == 2) {
            // v: bf16 transposed, pack 4 consecutive rows (j) into one 8B store
#pragma unroll
            for (int mt = 0; mt < 2; ++mt) {
                ushortx4 pv;
#pragma unroll
                for (int r = 0; r < 4; ++r) pv[r] = f2bf(qacc[mt][nt][r] + bb);
                *(ushortx4*)(vt + (size_t)col * 8192 + i0 + mt * 16 + lk * 4) = pv;
            }
        } else {
            float sc = (tt == 0) ? QSCALE : 1.0f;
            unsigned short* dst = (tt == 0) ? q : kt;
#pragma unroll
            for (int mt = 0; mt < 2; ++mt)
#pragma unroll
                for (int r = 0; r < 4; ++r)
                    dst[(size_t)(i0 + mt * 16 + lk * 4 + r) * 128 + col] = f2bf((qacc[mt][nt][r] + bb) * sc);
        }
    }
}

// ---------- K3: flash attention v4 (bf16, 2 blocks/CU, reg-prefetch single-buffer LDS) ----------
// grid (64, nsplit) x 256 thr; block = 128 Q rows, 4 waves, wave w owns q-rows w*32..+32.
// Per 64-j tile: barrier; ds_write prefetched K/V; issue global prefetch of next tile; barrier;
// S^T = K@Q^T -> P=exp2(S) -> wave-private Pt -> O += P@V (no intra-compute barrier).
// Two co-resident blocks per CU de-lock-step the MFMA/VALU/LDS phases.
static constexpr int KS = 0;          // [64][136] shorts (17408 B)
static constexpr int VS = 8704;       // [128][72] shorts (18432 B)
static constexpr int PS = 17920;      // [128][72] shorts (18432 B)
__global__ __launch_bounds__(256, 2) void k_flash(const unsigned short* __restrict__ qg,
                                                  const unsigned short* __restrict__ kg,
                                                  const unsigned short* __restrict__ vtg,
                                                  float* __restrict__ op,
                                                  float* __restrict__ lp,
                                                  int jrange) {
    __shared__ __align__(16) unsigned short lds[27136];   // 54272 B
    const int tid = threadIdx.x;
    const int i0 = blockIdx.x * 128;
    const int w = tid >> 6, lane = tid & 63;
    const int lr = lane & 15, lk = lane >> 4;

    // Q fragments (bf16, pre-scaled) in registers: rows w*32..+32
    short8 qf[2][4];
#pragma unroll
    for (int mt = 0; mt < 2; ++mt)
#pragma unroll
        for (int ks = 0; ks < 4; ++ks)
            qf[mt][ks] = *(const short8*)(qg + (size_t)(i0 + w * 32 + mt * 16 + lr) * 128 + ks * 32 + lk * 8);

    floatx4 oacc[2][8];
    float lsum[2] = {0.f, 0.f};
#pragma unroll
    for (int mt = 0; mt < 2; ++mt)
#pragma unroll
        for (int dt = 0; dt < 8; ++dt) oacc[mt][dt] = (floatx4)0.0f;

    const int jbase = blockIdx.y * jrange;
    const int ntile = jrange >> 6;
    const int krow = tid >> 2, kq = (tid & 3) << 5;   // K: 64 rows, 4 thr/row, 32 shorts each
    const int vrow = tid >> 1, vq = (tid & 1) << 5;   // V^T: 128 rows, 2 thr/row, 32 shorts each

    short8 pk4[4], pv4[4];
    {   // prefetch tile 0 into registers
        const unsigned short* gk = kg + (size_t)(jbase + krow) * 128 + kq;
        const unsigned short* gv = vtg + (size_t)vrow * 8192 + jbase + vq;
#pragma unroll
        for (int i = 0; i < 4; ++i) { pk4[i] = *(const short8*)(gk + i * 8); pv4[i] = *(const short8*)(gv + i * 8); }
    }

    for (int jt = 0; jt < ntile; ++jt) {
        __syncthreads();                 // previous tile's compute done; LDS free
        {   // commit prefetched tile to LDS
            unsigned short* dk = lds + KS + krow * 136 + kq;
            unsigned short* dv = lds + VS + vrow * 72 + vq;
#pragma unroll
            for (int i = 0; i < 4; ++i) { *(short8*)(dk + i * 8) = pk4[i]; *(short8*)(dv + i * 8) = pv4[i]; }
        }
        if (jt + 1 < ntile) {            // issue global prefetch of next tile (lands during compute)
            int j0 = jbase + (jt + 1) * 64;
            const unsigned short* gk = kg + (size_t)(j0 + krow) * 128 + kq;
            const unsigned short* gv = vtg + (size_t)vrow * 8192 + j0 + vq;
#pragma unroll
            for (int i = 0; i < 4; ++i) { pk4[i] = *(const short8*)(gk + i * 8); pv4[i] = *(const short8*)(gv + i * 8); }
        }
        __syncthreads();                 // staging visible

        // S^T = K @ Q^T : 64 j rows x this wave's 32 m cols
        floatx4 sacc[4][2];
#pragma unroll
        for (int j4 = 0; j4 < 4; ++j4) { sacc[j4][0] = (floatx4)0.0f; sacc[j4][1] = (floatx4)0.0f; }
#pragma unroll
        for (int ks = 0; ks < 4; ++ks) {
            short8 af[4];
#pragma unroll
            for (int j4 = 0; j4 < 4; ++j4)
                af[j4] = *(const short8*)(lds + KS + (j4 * 16 + lr) * 136 + ks * 32 + lk * 8);
#pragma unroll
            for (int j4 = 0; j4 < 4; ++j4)
#pragma unroll
                for (int mt = 0; mt < 2; ++mt)
                    sacc[j4][mt] = MFMA16(af[j4], qf[mt][ks], sacc[j4][mt]);
        }
        // P = exp2(S) -> bf16 wave-private Pt rows; accumulate l
#pragma unroll
        for (int mt = 0; mt < 2; ++mt) {
            unsigned short* prow = lds + PS + (w * 32 + mt * 16 + lr) * 72;
            float ls = 0.f;
#pragma unroll
            for (int j4 = 0; j4 < 4; ++j4) {
                float p0 = __builtin_amdgcn_exp2f(sacc[j4][mt][0]);
                float p1 = __builtin_amdgcn_exp2f(sacc[j4][mt][1]);
                float p2 = __builtin_amdgcn_exp2f(sacc[j4][mt][2]);
                float p3 = __builtin_amdgcn_exp2f(sacc[j4][mt][3]);
                ls += (p0 + p1) + (p2 + p3);
                uint2 pk;
                pk.x = packbf(p0, p1);
                pk.y = packbf(p2, p3);
                *(uint2*)(prow + j4 * 16 + lk * 4) = pk;
            }
            lsum[mt] += ls;
        }
        // O += P @ V (own Pt rows + shared Vs; wave-order DS guarantees RAW)
#pragma unroll
        for (int k2 = 0; k2 < 2; ++k2) {
            short8 pa[2], vb[8];
#pragma unroll
            for (int mt = 0; mt < 2; ++mt)
                pa[mt] = *(const short8*)(lds + PS + (w * 32 + mt * 16 + lr) * 72 + k2 * 32 + lk * 8);
#pragma unroll
            for (int dt = 0; dt < 8; ++dt)
                vb[dt] = *(const short8*)(lds + VS + (dt * 16 + lr) * 72 + k2 * 32 + lk * 8);
#pragma unroll
            for (int mt = 0; mt < 2; ++mt)
#pragma unroll
                for (int dt = 0; dt < 8; ++dt)
                    oacc[mt][dt] = MFMA16(pa[mt], vb[dt], oacc[mt][dt]);
        }
    }

    // l partials
#pragma unroll
    for (int mt = 0; mt < 2; ++mt) {
        float v = lsum[mt];
        v += __shfl_xor(v, 16);
        v += __shfl_xor(v, 32);
        if (lk == 0)
            lp[(size_t)blockIdx.y * 8192 + i0 + w * 32 + mt * 16 + lr] = v;
    }
    // O partials
    float* obase = op + ((size_t)blockIdx.y << 20);
#pragma unroll
    for (int mt = 0; mt < 2; ++mt)
#pragma unroll
        for (int dt = 0; dt < 8; ++dt)
#pragma unroll
            for (int r = 0; r < 4; ++r)
                obase[(size_t)(i0 + w * 32 + mt * 16 + lk * 4 + r) * 128 + dt * 16 + lr] = oacc[mt][dt][r];
}

// ---------- K4: out = ((sum_s O_s) / (sum_s l_s)) @ W_out + b_out ----------
__global__ __launch_bounds__(256) void k_out(const float* __restrict__ op,
                                             const float* __restrict__ lp,
                                             const float* __restrict__ wout,
                                             const float* __restrict__ bout,
                                             float* __restrict__ out, int nsplit) {
    const int tid = threadIdx.x;
    const int w = tid >> 6, lane = tid & 63;
    const int base = blockIdx.x * 16 + w * 4;
    float w1 = wout[lane], w2 = wout[lane + 64];
    for (int i = 0; i < 4; ++i) {
        int row = base + i;
        float o1 = 0.f, o2 = 0.f;
        for (int s = 0; s < nsplit; ++s) {
            const float* p = op + ((size_t)s << 20) + (size_t)row * 128;
            o1 += p[lane]; o2 += p[lane + 64];
        }
        float l = 0.f;
        for (int t = 0; t < nsplit; ++t) l += lp[(size_t)t * 8192 + row];
        float val = o1 * w1 + o2 * w2;
#pragma unroll
        for (int d = 1; d < 64; d <<= 1) val += __shfl_xor(val, d);
        if (lane == 0) out[row] = val / l + bout[0];
    }
}

// ---------- launch ----------
extern "C" void kernel_launch(void* const* d_in, const int* in_sizes, int n_in,
                              void* d_out, int out_size, void* d_ws, size_t ws_size,
                              hipStream_t stream) {
    const float* x    = (const float*)d_in[0];
    const float* Wfc  = (const float*)d_in[1];
    const float* bfc  = (const float*)d_in[2];
    const float* Wg   = (const float*)d_in[3];
    const float* bg   = (const float*)d_in[4];
    const float* Wq   = (const float*)d_in[5];
    const float* bq   = (const float*)d_in[6];
    const float* Wk   = (const float*)d_in[7];
    const float* bk   = (const float*)d_in[8];
    const float* Wv   = (const float*)d_in[9];
    const float* bv   = (const float*)d_in[10];
    const float* Wout = (const float*)d_in[11];
    const float* bout = (const float*)d_in[12];
    char* ws = (char*)d_ws;

    unsigned short* qb   = (unsigned short*)(ws + Q_OFF);
    unsigned short* kb   = (unsigned short*)(ws + K_OFF);
    unsigned short* vtb  = (unsigned short*)(ws + VT_OFF);
    unsigned short* wfct = (unsigned short*)(ws + WFCT_OFF);
    unsigned short* wgt  = (unsigned short*)(ws + WGT_OFF);
    unsigned short* wqt  = (unsigned short*)(ws + WQT_OFF);
    unsigned short* wkt  = (unsigned short*)(ws + WKT_OFF);
    unsigned short* wvt  = (unsigned short*)(ws + WVT_OFF);
    float* lpb = (float*)(ws + LP_OFF);
    float* opb = (float*)(ws + OP_OFF);

    int nsplit = 1;
    if (ws_size >= OP_OFF + ((size_t)8 << 22)) nsplit = 8;
    else if (ws_size >= OP_OFF + ((size_t)4 << 22)) nsplit = 4;
    else if (ws_size >= OP_OFF + ((size_t)2 << 22)) nsplit = 2;

    k_transw_all<<<1216, 256, 0, stream>>>(Wfc, Wg, Wq, Wk, Wv, wfct, wgt, wqt, wkt, wvt);
    k_gq<<<256, 512, 0, stream>>>(x, wfct, wgt, bfc, bg, wqt, wkt, wvt, bq, bk, bv, qb, kb, vtb);

    dim3 gf(64, nsplit);
    k_flash<<<gf, 256, 0, stream>>>(qb, kb, vtb, opb, lpb, 8192 / nsplit);

    k_out<<<512, 256, 0, stream>>>(opb, lpb, Wout, bout, (float*)d_out, nsplit);
}